// Round 1
// baseline (1293.448 us; speedup 1.0000x reference)
//
#include <hip/hip_runtime.h>
#include <hip/hip_bf16.h>

// ---------------- problem constants ----------------
#define N_LEAVES   65536            // 4^8
#define N_INTERNAL 21845            // (4^8-1)/3
#define IN_DIM     64
#define MEM        128
#define HID        128
#define CHUNK      8192             // leaf-MLP row chunk

// ---------------- GEMM + tanh: C[M][N] = tanh(A[M][K] @ W[N][K]^T) ----------------
#define TM 64
#define TN 64
#define TK 16

__global__ __launch_bounds__(256) void gemm_tanh_kernel(
    const float* __restrict__ A, const float* __restrict__ W,
    float* __restrict__ C, int M, int N, int K)
{
    __shared__ float As[TK][TM + 1];
    __shared__ float Ws[TK][TN + 1];

    const int bm = blockIdx.x * TM;
    const int bn = blockIdx.y * TN;
    const int tid = threadIdx.x;
    const int tx = tid & 15;         // 0..15 -> output cols
    const int ty = tid >> 4;         // 0..15 -> output rows

    float acc[4][4] = {};

    for (int k0 = 0; k0 < K; k0 += TK) {
        // load A tile (TM x TK) and W tile (TN x TK), stored k-major
        #pragma unroll
        for (int i = tid; i < TM * TK; i += 256) {
            int m = i >> 4, kk = i & 15;
            As[kk][m] = A[(size_t)(bm + m) * K + k0 + kk];
        }
        #pragma unroll
        for (int i = tid; i < TN * TK; i += 256) {
            int n = i >> 4, kk = i & 15;
            Ws[kk][n] = W[(size_t)(bn + n) * K + k0 + kk];
        }
        __syncthreads();

        #pragma unroll
        for (int kk = 0; kk < TK; ++kk) {
            float a[4], w[4];
            #pragma unroll
            for (int i = 0; i < 4; ++i) a[i] = As[kk][ty * 4 + i];
            #pragma unroll
            for (int j = 0; j < 4; ++j) w[j] = Ws[kk][tx * 4 + j];
            #pragma unroll
            for (int i = 0; i < 4; ++i)
                #pragma unroll
                for (int j = 0; j < 4; ++j)
                    acc[i][j] += a[i] * w[j];
        }
        __syncthreads();
    }

    #pragma unroll
    for (int i = 0; i < 4; ++i) {
        int m = bm + ty * 4 + i;
        #pragma unroll
        for (int j = 0; j < 4; ++j) {
            int n = bn + tx * 4 + j;
            C[(size_t)m * N + n] = tanhf(acc[i][j]);
        }
    }
}

// ---------------- tree level kernel ----------------
// Hout[p][o] = 0.25 * sum_c tanh( dot(Hin[4p+c][:], Wsel[o][:]) ),
// Wsel = (ops[p]==0) ? Wand : Wor
#define TREE_P 8    // parents per block

__global__ __launch_bounds__(256) void tree_kernel(
    const float* __restrict__ Hin,   // [nparents*4][MEM]
    float* __restrict__ Hout,        // [nparents][MEM]
    const int* __restrict__ ops,     // per-parent op for this level
    const float* __restrict__ Wand,  // [MEM][MEM]
    const float* __restrict__ Wor,   // [MEM][MEM]
    int nparents)
{
    __shared__ float Wl[2][MEM][MEM + 1];       // padded: conflict-free reads
    __shared__ float ch[TREE_P][4][MEM];
    __shared__ int   opsh[TREE_P];

    const int tid = threadIdx.x;

    // stage both weight matrices (coalesced global reads)
    for (int i = tid; i < MEM * MEM; i += 256) {
        int o = i >> 7, m = i & 127;
        Wl[0][o][m] = Wand[i];
        Wl[1][o][m] = Wor[i];
    }

    const int p0 = blockIdx.x * TREE_P;
    const int nload = min(TREE_P, nparents - p0);

    for (int i = tid; i < nload * 4 * MEM; i += 256)
        ch[0][0][i] = Hin[(size_t)p0 * 4 * MEM + i];
    if (tid < nload) opsh[tid] = ops[p0 + tid];
    __syncthreads();

    const int o = tid & 127;          // output index
    const int half = tid >> 7;        // 0: parents 0..3, 1: parents 4..7

    float acc[4][4] = {};             // [parent-in-half][child]

    for (int m = 0; m < MEM; ++m) {
        float wa = Wl[0][o][m];
        float wo = Wl[1][o][m];
        #pragma unroll
        for (int pp = 0; pp < 4; ++pp) {
            int p = half * 4 + pp;
            float w = (opsh[p] == 0) ? wa : wo;
            #pragma unroll
            for (int c = 0; c < 4; ++c)
                acc[pp][c] += ch[p][c][m] * w;
        }
    }

    #pragma unroll
    for (int pp = 0; pp < 4; ++pp) {
        int p = half * 4 + pp;
        if (p0 + p < nparents) {
            float s = 0.f;
            #pragma unroll
            for (int c = 0; c < 4; ++c) s += tanhf(acc[pp][c]);
            Hout[(size_t)(p0 + p) * MEM + o] = 0.25f * s;
        }
    }
}

// ---------------- readout: 1x128 -> relu mlp -> scalar ----------------
__global__ __launch_bounds__(128) void readout_kernel(
    const float* __restrict__ h,      // [128] root
    const float* __restrict__ Rw1, const float* __restrict__ Rb1,
    const float* __restrict__ Rw2, const float* __restrict__ Rb2,
    const float* __restrict__ Rw3, const float* __restrict__ Rb3,
    const float* __restrict__ Rwp, const float* __restrict__ Rbp,
    float* __restrict__ out)
{
    __shared__ float x0[HID], x1[HID], x2[HID], x3[HID], red[HID];
    const int o = threadIdx.x;

    x0[o] = h[o];
    __syncthreads();

    float s = 0.f;
    for (int m = 0; m < HID; ++m) s += Rw1[o * HID + m] * x0[m];
    x1[o] = fmaxf(s + Rb1[o], 0.f);
    __syncthreads();

    s = 0.f;
    for (int m = 0; m < HID; ++m) s += Rw2[o * HID + m] * x1[m];
    x2[o] = fmaxf(s + Rb2[o], 0.f);
    __syncthreads();

    s = 0.f;
    for (int m = 0; m < HID; ++m) s += Rw3[o * HID + m] * x2[m];
    x3[o] = fmaxf(s + Rb3[o], 0.f);
    __syncthreads();

    red[o] = Rwp[o] * x3[o];
    __syncthreads();
    if (o < 64) red[o] += red[o + 64];
    __syncthreads();
    if (o == 0) {
        float t = 0.f;
        for (int i = 0; i < 64; ++i) t += red[i];
        out[0] = t + Rbp[0];
    }
}

// ---------------- host launch ----------------
extern "C" void kernel_launch(void* const* d_in, const int* in_sizes, int n_in,
                              void* d_out, int out_size, void* d_ws, size_t ws_size,
                              hipStream_t stream)
{
    const float* inputs = (const float*)d_in[0];
    const int*   ops    = (const int*)d_in[1];
    const float* W1     = (const float*)d_in[2];
    const float* W2     = (const float*)d_in[3];
    const float* W3     = (const float*)d_in[4];
    const float* Wp     = (const float*)d_in[5];
    const float* Wand   = (const float*)d_in[6];
    const float* Wor    = (const float*)d_in[7];
    const float* Rw1    = (const float*)d_in[8];
    const float* Rb1    = (const float*)d_in[9];
    const float* Rw2    = (const float*)d_in[10];
    const float* Rb2    = (const float*)d_in[11];
    const float* Rw3    = (const float*)d_in[12];
    const float* Rb3    = (const float*)d_in[13];
    const float* Rwp    = (const float*)d_in[14];
    const float* Rbp    = (const float*)d_in[15];
    float* out = (float*)d_out;
    float* ws  = (float*)d_ws;

    // workspace layout (floats):
    //   h4    : N_LEAVES * MEM            (8.39M)  leaf-MLP final output
    //   pA    : CHUNK * 384               (3.15M)  ping
    //   pB    : CHUNK * 384               (3.15M)  pong
    float* h4 = ws;
    float* pA = ws + (size_t)N_LEAVES * MEM;
    float* pB = pA + (size_t)CHUNK * 384;

    // ---- leaf MLP, chunked over rows ----
    for (int c0 = 0; c0 < N_LEAVES; c0 += CHUNK) {
        const float* in_c = inputs + (size_t)c0 * IN_DIM;
        gemm_tanh_kernel<<<dim3(CHUNK / TM, 128 / TN), 256, 0, stream>>>(in_c, W1, pA, CHUNK, 128, 64);
        gemm_tanh_kernel<<<dim3(CHUNK / TM, 384 / TN), 256, 0, stream>>>(pA, W2, pB, CHUNK, 384, 128);
        gemm_tanh_kernel<<<dim3(CHUNK / TM, 256 / TN), 256, 0, stream>>>(pB, W3, pA, CHUNK, 256, 384);
        gemm_tanh_kernel<<<dim3(CHUNK / TM, 128 / TN), 256, 0, stream>>>(pA, Wp, h4 + (size_t)c0 * MEM, CHUNK, 128, 256);
    }

    // ---- tree reduction, level 7 down to 0 ----
    const float* hin = h4;
    float* cur = pA;
    float* nxt = pB;
    for (int l = 7; l >= 0; --l) {
        int n = 1;
        for (int i = 0; i < l; ++i) n *= 4;      // 4^l parents
        int start = (n - 1) / 3;                 // (4^l - 1)/(4-1)
        int blocks = (n + TREE_P - 1) / TREE_P;
        tree_kernel<<<blocks, 256, 0, stream>>>(hin, cur, ops + start, Wand, Wor, n);
        hin = cur;
        float* t = cur; cur = nxt; nxt = t;
    }

    // ---- readout on root ----
    readout_kernel<<<1, 128, 0, stream>>>(hin, Rw1, Rb1, Rw2, Rb2, Rw3, Rb3, Rwp, Rbp, out);
}

// Round 2
// 575.481 us; speedup vs baseline: 2.2476x; 2.2476x over previous
//
#include <hip/hip_runtime.h>
#include <hip/hip_bf16.h>

// ---------------- problem constants ----------------
#define N_LEAVES   65536            // 4^8
#define IN_DIM     64
#define MEM        128
#define HID        128

// ---------------- fused GEMM:  C = epilogue(A[M][K] @ W[N][K]^T) ----------------
// EPI=0 (leaf):  C[m][n] = tanh(dot)           , C is [M][N]
// EPI=1 (tree):  C[p][n] = 0.25*sum_{i<4} tanh(dot(row 4p+i)) with W selected
//                per parent by ops[p] (0 -> W0, else W1), C is [M/4][128]
#define TM  128
#define TN  128
#define TKK 16
#define LDP 132                      // padded LDS row stride (floats)

template<int EPI>
__global__ __launch_bounds__(256) void gemm_fused(
    const float* __restrict__ A,
    const float* __restrict__ W0,    // [N][K] row-major
    const float* __restrict__ W1,    // tree only
    const int*   __restrict__ ops,   // tree only, per parent of this level
    float* __restrict__ C,
    int M, int N, int K)
{
    __shared__ float As[TKK * LDP];
    __shared__ float Ws[2][TKK * LDP];

    const int bm  = blockIdx.x * TM;
    const int bn  = blockIdx.y * TN;
    const int tid = threadIdx.x;
    const int cg  = tid & 7;         // col group  (16 cols each)
    const int tg  = tid >> 3;        // row group  (4 rows each, 0..31)

    // per-thread weight select (tree): thread's 4 rows are exactly one parent
    int op = 0;
    if (EPI == 1) {
        int p = (bm >> 2) + tg;
        op = (p < (M >> 2)) ? ops[p] : 0;
    }

    float acc[4][16] = {};

    for (int k0 = 0; k0 < K; k0 += TKK) {
        // ---- stage A tile: TM x TKK (k-major in LDS) ----
        #pragma unroll
        for (int f = 0; f < 2; ++f) {
            int fi = tid + f * 256;            // float4 index 0..511
            int m  = fi >> 2;
            int kk = (fi & 3) * 4;
            float4 v = make_float4(0.f, 0.f, 0.f, 0.f);
            if (bm + m < M)
                v = *(const float4*)&A[(size_t)(bm + m) * K + k0 + kk];
            As[(kk + 0) * LDP + m] = v.x;
            As[(kk + 1) * LDP + m] = v.y;
            As[(kk + 2) * LDP + m] = v.z;
            As[(kk + 3) * LDP + m] = v.w;
        }
        // ---- stage W tile(s): TN x TKK (k-major in LDS) ----
        #pragma unroll
        for (int f = 0; f < 2; ++f) {
            int fi = tid + f * 256;
            int n  = fi >> 2;
            int kk = (fi & 3) * 4;
            float4 v = *(const float4*)&W0[(size_t)(bn + n) * K + k0 + kk];
            Ws[0][(kk + 0) * LDP + n] = v.x;
            Ws[0][(kk + 1) * LDP + n] = v.y;
            Ws[0][(kk + 2) * LDP + n] = v.z;
            Ws[0][(kk + 3) * LDP + n] = v.w;
            if (EPI == 1) {
                float4 u = *(const float4*)&W1[(size_t)(bn + n) * K + k0 + kk];
                Ws[1][(kk + 0) * LDP + n] = u.x;
                Ws[1][(kk + 1) * LDP + n] = u.y;
                Ws[1][(kk + 2) * LDP + n] = u.z;
                Ws[1][(kk + 3) * LDP + n] = u.w;
            }
        }
        __syncthreads();

        const float* Wbase = (EPI == 1 && op) ? &Ws[1][0] : &Ws[0][0];

        #pragma unroll
        for (int kk = 0; kk < TKK; ++kk) {
            float4 av = *(const float4*)&As[kk * LDP + tg * 4];
            float a[4] = {av.x, av.y, av.z, av.w};
            // rotated W reads (bank-conflict dodge); register/acc indices stay
            // STATIC — only the LDS *address* and output column are rotated.
            float w[16];
            #pragma unroll
            for (int j4 = 0; j4 < 4; ++j4) {
                int jj = (j4 + cg) & 3;        // address rotation only
                float4 wv = *(const float4*)&Wbase[kk * LDP + cg * 16 + jj * 4];
                w[j4 * 4 + 0] = wv.x; w[j4 * 4 + 1] = wv.y;
                w[j4 * 4 + 2] = wv.z; w[j4 * 4 + 3] = wv.w;
            }
            #pragma unroll
            for (int i = 0; i < 4; ++i)
                #pragma unroll
                for (int j = 0; j < 16; ++j)
                    acc[i][j] = fmaf(a[i], w[j], acc[i][j]);
        }
        __syncthreads();
    }

    if (EPI == 0) {
        #pragma unroll
        for (int i = 0; i < 4; ++i) {
            int m = bm + tg * 4 + i;
            if (m < M) {
                #pragma unroll
                for (int j4 = 0; j4 < 4; ++j4) {
                    int jj = (j4 + cg) & 3;    // undo column rotation
                    float4 o;
                    o.x = tanhf(acc[i][j4 * 4 + 0]);
                    o.y = tanhf(acc[i][j4 * 4 + 1]);
                    o.z = tanhf(acc[i][j4 * 4 + 2]);
                    o.w = tanhf(acc[i][j4 * 4 + 3]);
                    *(float4*)&C[(size_t)m * N + bn + cg * 16 + jj * 4] = o;
                }
            }
        }
    } else {
        int p = (bm >> 2) + tg;
        if (p < (M >> 2)) {
            #pragma unroll
            for (int j4 = 0; j4 < 4; ++j4) {
                int jj = (j4 + cg) & 3;
                float4 o;
                o.x = 0.25f * (tanhf(acc[0][j4*4+0]) + tanhf(acc[1][j4*4+0]) + tanhf(acc[2][j4*4+0]) + tanhf(acc[3][j4*4+0]));
                o.y = 0.25f * (tanhf(acc[0][j4*4+1]) + tanhf(acc[1][j4*4+1]) + tanhf(acc[2][j4*4+1]) + tanhf(acc[3][j4*4+1]));
                o.z = 0.25f * (tanhf(acc[0][j4*4+2]) + tanhf(acc[1][j4*4+2]) + tanhf(acc[2][j4*4+2]) + tanhf(acc[3][j4*4+2]));
                o.w = 0.25f * (tanhf(acc[0][j4*4+3]) + tanhf(acc[1][j4*4+3]) + tanhf(acc[2][j4*4+3]) + tanhf(acc[3][j4*4+3]));
                *(float4*)&C[(size_t)p * MEM + cg * 16 + jj * 4] = o;
            }
        }
    }
}

// ---------------- readout: 1x128 -> relu mlp -> scalar ----------------
__global__ __launch_bounds__(128) void readout_kernel(
    const float* __restrict__ h,
    const float* __restrict__ Rw1, const float* __restrict__ Rb1,
    const float* __restrict__ Rw2, const float* __restrict__ Rb2,
    const float* __restrict__ Rw3, const float* __restrict__ Rb3,
    const float* __restrict__ Rwp, const float* __restrict__ Rbp,
    float* __restrict__ out)
{
    __shared__ float x0[HID], x1[HID], x2[HID], x3[HID], red[HID];
    const int o = threadIdx.x;

    x0[o] = h[o];
    __syncthreads();

    float s = 0.f;
    for (int m = 0; m < HID; ++m) s += Rw1[o * HID + m] * x0[m];
    x1[o] = fmaxf(s + Rb1[o], 0.f);
    __syncthreads();

    s = 0.f;
    for (int m = 0; m < HID; ++m) s += Rw2[o * HID + m] * x1[m];
    x2[o] = fmaxf(s + Rb2[o], 0.f);
    __syncthreads();

    s = 0.f;
    for (int m = 0; m < HID; ++m) s += Rw3[o * HID + m] * x2[m];
    x3[o] = fmaxf(s + Rb3[o], 0.f);
    __syncthreads();

    red[o] = Rwp[o] * x3[o];
    __syncthreads();
    if (o < 64) red[o] += red[o + 64];
    __syncthreads();
    if (o == 0) {
        float t = 0.f;
        for (int i = 0; i < 64; ++i) t += red[i];
        out[0] = t + Rbp[0];
    }
}

// ---------------- host launch ----------------
extern "C" void kernel_launch(void* const* d_in, const int* in_sizes, int n_in,
                              void* d_out, int out_size, void* d_ws, size_t ws_size,
                              hipStream_t stream)
{
    const float* inputs = (const float*)d_in[0];
    const int*   ops    = (const int*)d_in[1];
    const float* W1     = (const float*)d_in[2];
    const float* W2     = (const float*)d_in[3];
    const float* W3     = (const float*)d_in[4];
    const float* Wp     = (const float*)d_in[5];
    const float* Wand   = (const float*)d_in[6];
    const float* Wor    = (const float*)d_in[7];
    const float* Rw1    = (const float*)d_in[8];
    const float* Rb1    = (const float*)d_in[9];
    const float* Rw2    = (const float*)d_in[10];
    const float* Rb2    = (const float*)d_in[11];
    const float* Rw3    = (const float*)d_in[12];
    const float* Rb3    = (const float*)d_in[13];
    const float* Rwp    = (const float*)d_in[14];
    const float* Rbp    = (const float*)d_in[15];
    float* out = (float*)d_out;
    float* ws  = (float*)d_ws;

    // workspace: h4 [65536*128] + two ping-pong buffers [chunk*384]
    const size_t h4_elems = (size_t)N_LEAVES * MEM;
    int chunk = 8192;
    {
        size_t full_bytes = (h4_elems + 2 * (size_t)N_LEAVES * 384) * sizeof(float);
        if (ws_size >= full_bytes) chunk = N_LEAVES;
    }
    float* h4 = ws;
    float* pA = ws + h4_elems;
    float* pB = pA + (size_t)chunk * 384;

    // ---- leaf MLP ----
    for (int c0 = 0; c0 < N_LEAVES; c0 += chunk) {
        const float* in_c = inputs + (size_t)c0 * IN_DIM;
        gemm_fused<0><<<dim3(chunk / TM, 1), 256, 0, stream>>>(in_c, W1, nullptr, nullptr, pA, chunk, 128, 64);
        gemm_fused<0><<<dim3(chunk / TM, 3), 256, 0, stream>>>(pA, W2, nullptr, nullptr, pB, chunk, 384, 128);
        gemm_fused<0><<<dim3(chunk / TM, 2), 256, 0, stream>>>(pB, W3, nullptr, nullptr, pA, chunk, 256, 384);
        gemm_fused<0><<<dim3(chunk / TM, 1), 256, 0, stream>>>(pA, Wp, nullptr, nullptr, h4 + (size_t)c0 * MEM, chunk, 128, 256);
    }

    // ---- tree reduction, level 7 down to 0 ----
    const float* hin = h4;
    float* cur = pA;
    float* nxt = pB;
    for (int l = 7; l >= 0; --l) {
        int n = 1 << (2 * l);                 // 4^l parents
        int start = (n - 1) / 3;
        int Mrows = 4 * n;                    // children rows
        int blocks = (Mrows + TM - 1) / TM;
        gemm_fused<1><<<dim3(blocks, 1), 256, 0, stream>>>(hin, Wand, Wor, ops + start, cur, Mrows, 128, 128);
        hin = cur;
        float* t = cur; cur = nxt; nxt = t;
    }

    // ---- readout ----
    readout_kernel<<<1, 128, 0, stream>>>(hin, Rw1, Rb1, Rw2, Rb2, Rw3, Rb3, Rwp, Rbp, out);
}

// Round 3
// 276.510 us; speedup vs baseline: 4.6778x; 2.0812x over previous
//
#include <hip/hip_runtime.h>
#include <hip/hip_bf16.h>

#define N_LEAVES 65536
#define MEM 128
#define HID 128

typedef float  f32x4 __attribute__((ext_vector_type(4)));
typedef short  s16x8 __attribute__((ext_vector_type(8)));
typedef unsigned short u16;
typedef u16    u16x8 __attribute__((ext_vector_type(8)));

__device__ __forceinline__ u16 f2bf(float x) {
    unsigned u = __builtin_bit_cast(unsigned, x);
    u += 0x7FFFu + ((u >> 16) & 1u);          // round-to-nearest-even
    return (u16)(u >> 16);
}
__device__ __forceinline__ float bf2f(u16 b) {
    unsigned u = ((unsigned)b) << 16;
    return __builtin_bit_cast(float, u);
}
// tanh with full RELATIVE accuracy for small |x| (deep-tree activations ~1e-5:
// the 1-2/(E+1) form alone has an ulp(1)~1e-7 ABSOLUTE floor = 1% rel there).
__device__ __forceinline__ float tanh_p(float x) {
    float x2 = x * x;
    float poly = x * (1.0f + x2 * (-0.33333334f + x2 * 0.13333334f)); // |x|<0.25: rel err ~1e-5
    float E = __builtin_amdgcn_exp2f(x * 2.8853900817779268f);        // exp(2x)
    float ex = 1.0f - 2.0f / (E + 1.0f);                              // |x|>=0.25: rel err ~5e-7
    return (__builtin_fabsf(x) < 0.25f) ? poly : ex;
}

// ---------------- split fp32 -> bf16 hi/lo planes ----------------
__global__ __launch_bounds__(256) void split_kernel(
    const float* __restrict__ src, u16* __restrict__ hi, u16* __restrict__ lo, int n)
{
    int i = blockIdx.x * 256 + threadIdx.x;
    int stride = gridDim.x * 256;
    for (; i < n; i += stride) {
        float x = src[i];
        u16 h = f2bf(x);
        float r = x - bf2f(h);
        hi[i] = h;
        lo[i] = f2bf(r);
    }
}

// LDS swizzle: 16B granule, slot = chunk ^ (row&3) ^ ((row>>2)&3) -> <=2-way reads
__device__ __forceinline__ int swz(int row, int ch) {
    int slot = (ch ^ (row & 3) ^ ((row >> 2) & 3)) & 3;
    return row * 32 + slot * 8;    // u16 offset; row stride 32 u16 = 64B
}

// ---------------- split-bf16 MFMA GEMM: C = epi(A[M][K] @ W[N][K]^T) ----------------
// EPI=0 leaf: C[m][n] = tanh(dot), planes [M][N]
// EPI=1 tree: C[p][n] = 0.25*sum_{r<4} tanh(dot(row 4p+r)), W selected by ops[p]
template<int EPI>
__global__ __launch_bounds__(256, 2) void gemm_bf(
    const u16* __restrict__ Ah, const u16* __restrict__ Al,
    const u16* __restrict__ B0h, const u16* __restrict__ B0l,
    const u16* __restrict__ B1h, const u16* __restrict__ B1l,
    const int* __restrict__ ops,
    u16* __restrict__ Ch, u16* __restrict__ Cl,
    int M, int N, int K)
{
    __shared__ u16 sAh[4096], sAl[4096], sBh[4096], sBl[4096];
    __shared__ u16 sB2h[EPI ? 4096 : 8], sB2l[EPI ? 4096 : 8];

    const int tid = threadIdx.x;
    const int l   = tid & 63;
    const int wv  = tid >> 6;
    const int wm  = wv >> 1, wn = wv & 1;
    const int lr  = l & 15;          // fragment row (A) / col (B)
    const int lc  = l >> 4;          // k-chunk 0..3
    const int bm  = blockIdx.x * 128;
    const int bn  = blockIdx.y * 128;

    const int Arows = (M - bm < 128) ? (M - bm) : 128;

    f32x4 acc0[4][4] = {};
    f32x4 acc1[4][4] = {};           // tree only; DCE'd for leaf

    for (int k0 = 0; k0 < K; k0 += 32) {
        // ---- stage A planes (128 x 32) ----
        #pragma unroll
        for (int f = 0; f < 2; ++f) {
            int fi = tid + f * 256;          // 512 chunks of 8 u16
            int row = fi >> 2, ch = fi & 3;
            int so = swz(row, ch);
            u16x8 vh = {0,0,0,0,0,0,0,0}, vl = {0,0,0,0,0,0,0,0};
            if (row < Arows) {
                size_t g = (size_t)(bm + row) * K + k0 + ch * 8;
                vh = *(const u16x8*)&Ah[g];
                vl = *(const u16x8*)&Al[g];
            }
            *(u16x8*)&sAh[so] = vh;
            *(u16x8*)&sAl[so] = vl;
        }
        // ---- stage W planes ----
        #pragma unroll
        for (int f = 0; f < 2; ++f) {
            int fi = tid + f * 256;
            int row = fi >> 2, ch = fi & 3;
            int so = swz(row, ch);
            size_t g = (size_t)(bn + row) * K + k0 + ch * 8;
            *(u16x8*)&sBh[so] = *(const u16x8*)&B0h[g];
            *(u16x8*)&sBl[so] = *(const u16x8*)&B0l[g];
        }
        if constexpr (EPI) {
            #pragma unroll
            for (int f = 0; f < 2; ++f) {
                int fi = tid + f * 256;
                int row = fi >> 2, ch = fi & 3;
                int so = swz(row, ch);
                size_t g = (size_t)(bn + row) * K + k0 + ch * 8;
                *(u16x8*)&sB2h[so] = *(const u16x8*)&B1h[g];
                *(u16x8*)&sB2l[so] = *(const u16x8*)&B1l[g];
            }
        }
        __syncthreads();

        s16x8 fah[4], fal[4];
        #pragma unroll
        for (int mi = 0; mi < 4; ++mi) {
            int row = wm * 64 + mi * 16 + lr;
            int so = swz(row, lc);
            fah[mi] = *(const s16x8*)&sAh[so];
            fal[mi] = *(const s16x8*)&sAl[so];
        }

        if constexpr (!EPI) {
            s16x8 fbh[4], fbl[4];
            #pragma unroll
            for (int nj = 0; nj < 4; ++nj) {
                int row = wn * 64 + nj * 16 + lr;
                int so = swz(row, lc);
                fbh[nj] = *(const s16x8*)&sBh[so];
                fbl[nj] = *(const s16x8*)&sBl[so];
            }
            #pragma unroll
            for (int mi = 0; mi < 4; ++mi)
                #pragma unroll
                for (int nj = 0; nj < 4; ++nj) {
                    f32x4 a = acc0[mi][nj];
                    a = __builtin_amdgcn_mfma_f32_16x16x32_bf16(fah[mi], fbh[nj], a, 0, 0, 0);
                    a = __builtin_amdgcn_mfma_f32_16x16x32_bf16(fah[mi], fbl[nj], a, 0, 0, 0);
                    a = __builtin_amdgcn_mfma_f32_16x16x32_bf16(fal[mi], fbh[nj], a, 0, 0, 0);
                    acc0[mi][nj] = a;
                }
        } else {
            #pragma unroll
            for (int nj = 0; nj < 4; ++nj) {
                int row = wn * 64 + nj * 16 + lr;
                int so = swz(row, lc);
                s16x8 b0h = *(const s16x8*)&sBh[so];
                s16x8 b0l = *(const s16x8*)&sBl[so];
                s16x8 b1h = *(const s16x8*)&sB2h[so];
                s16x8 b1l = *(const s16x8*)&sB2l[so];
                #pragma unroll
                for (int mi = 0; mi < 4; ++mi) {
                    f32x4 a = acc0[mi][nj];
                    a = __builtin_amdgcn_mfma_f32_16x16x32_bf16(fah[mi], b0h, a, 0, 0, 0);
                    a = __builtin_amdgcn_mfma_f32_16x16x32_bf16(fah[mi], b0l, a, 0, 0, 0);
                    a = __builtin_amdgcn_mfma_f32_16x16x32_bf16(fal[mi], b0h, a, 0, 0, 0);
                    acc0[mi][nj] = a;
                    f32x4 o = acc1[mi][nj];
                    o = __builtin_amdgcn_mfma_f32_16x16x32_bf16(fah[mi], b1h, o, 0, 0, 0);
                    o = __builtin_amdgcn_mfma_f32_16x16x32_bf16(fah[mi], b1l, o, 0, 0, 0);
                    o = __builtin_amdgcn_mfma_f32_16x16x32_bf16(fal[mi], b1h, o, 0, 0, 0);
                    acc1[mi][nj] = o;
                }
            }
        }
        __syncthreads();
    }

    if constexpr (!EPI) {
        #pragma unroll
        for (int mi = 0; mi < 4; ++mi)
            #pragma unroll
            for (int nj = 0; nj < 4; ++nj) {
                int col = bn + wn * 64 + nj * 16 + lr;
                f32x4 v = acc0[mi][nj];
                #pragma unroll
                for (int r = 0; r < 4; ++r) {
                    int m = bm + wm * 64 + mi * 16 + lc * 4 + r;
                    float t = tanh_p(v[r]);
                    u16 hb = f2bf(t);
                    float lo = t - bf2f(hb);
                    size_t g = (size_t)m * N + col;
                    Ch[g] = hb;
                    Cl[g] = f2bf(lo);
                }
            }
    } else {
        const int P = M >> 2;
        #pragma unroll
        for (int mi = 0; mi < 4; ++mi) {
            int p = (bm >> 2) + wm * 16 + mi * 4 + lc;   // lane's 4 D-rows = one parent
            if (p < P) {
                int op = ops[p];
                #pragma unroll
                for (int nj = 0; nj < 4; ++nj) {
                    int col = wn * 64 + nj * 16 + lr;
                    f32x4 v = op ? acc1[mi][nj] : acc0[mi][nj];
                    float t = 0.25f * (tanh_p(v[0]) + tanh_p(v[1]) + tanh_p(v[2]) + tanh_p(v[3]));
                    u16 hb = f2bf(t);
                    float lo = t - bf2f(hb);
                    size_t g = (size_t)p * 128 + col;
                    Ch[g] = hb;
                    Cl[g] = f2bf(lo);
                }
            }
        }
    }
}

// ---------------- readout: 1x128 -> relu mlp -> scalar ----------------
__global__ __launch_bounds__(128) void readout_kernel(
    const u16* __restrict__ hH, const u16* __restrict__ hL,
    const float* __restrict__ Rw1, const float* __restrict__ Rb1,
    const float* __restrict__ Rw2, const float* __restrict__ Rb2,
    const float* __restrict__ Rw3, const float* __restrict__ Rb3,
    const float* __restrict__ Rwp, const float* __restrict__ Rbp,
    float* __restrict__ out)
{
    __shared__ float x0[HID], x1[HID], x2[HID], x3[HID], red[HID];
    const int o = threadIdx.x;

    x0[o] = bf2f(hH[o]) + bf2f(hL[o]);
    __syncthreads();

    float s = 0.f;
    for (int m = 0; m < HID; ++m) s += Rw1[o * HID + m] * x0[m];
    x1[o] = fmaxf(s + Rb1[o], 0.f);
    __syncthreads();

    s = 0.f;
    for (int m = 0; m < HID; ++m) s += Rw2[o * HID + m] * x1[m];
    x2[o] = fmaxf(s + Rb2[o], 0.f);
    __syncthreads();

    s = 0.f;
    for (int m = 0; m < HID; ++m) s += Rw3[o * HID + m] * x2[m];
    x3[o] = fmaxf(s + Rb3[o], 0.f);
    __syncthreads();

    red[o] = Rwp[o] * x3[o];
    __syncthreads();
    if (o < 64) red[o] += red[o + 64];
    __syncthreads();
    if (o == 0) {
        float t = 0.f;
        for (int i = 0; i < 64; ++i) t += red[i];
        out[0] = t + Rbp[0];
    }
}

// ---------------- host launch ----------------
extern "C" void kernel_launch(void* const* d_in, const int* in_sizes, int n_in,
                              void* d_out, int out_size, void* d_ws, size_t ws_size,
                              hipStream_t stream)
{
    const float* inputs = (const float*)d_in[0];
    const int*   ops    = (const int*)d_in[1];
    const float* W1     = (const float*)d_in[2];
    const float* W2     = (const float*)d_in[3];
    const float* W3     = (const float*)d_in[4];
    const float* Wp     = (const float*)d_in[5];
    const float* Wand   = (const float*)d_in[6];
    const float* Wor    = (const float*)d_in[7];
    const float* Rw1    = (const float*)d_in[8];
    const float* Rb1    = (const float*)d_in[9];
    const float* Rw2    = (const float*)d_in[10];
    const float* Rb2    = (const float*)d_in[11];
    const float* Rw3    = (const float*)d_in[12];
    const float* Rb3    = (const float*)d_in[13];
    const float* Rwp    = (const float*)d_in[14];
    const float* Rbp    = (const float*)d_in[15];
    float* out = (float*)d_out;
    u16* ws = (u16*)d_ws;

    // ---- workspace layout (u16 elements) ----
    size_t off = 0;
    u16* inh = ws + off; off += (size_t)N_LEAVES * 64;
    u16* inl = ws + off; off += (size_t)N_LEAVES * 64;
    u16* w1h = ws + off; off += 8192;   u16* w1l = ws + off; off += 8192;
    u16* w2h = ws + off; off += 49152;  u16* w2l = ws + off; off += 49152;
    u16* w3h = ws + off; off += 98304;  u16* w3l = ws + off; off += 98304;
    u16* wph = ws + off; off += 32768;  u16* wpl = ws + off; off += 32768;
    u16* wah = ws + off; off += 16384;  u16* wal = ws + off; off += 16384;
    u16* woh = ws + off; off += 16384;  u16* wol = ws + off; off += 16384;
    u16* h4h = ws + off; off += (size_t)N_LEAVES * 128;
    u16* h4l = ws + off; off += (size_t)N_LEAVES * 128;

    const size_t fixed = off;
    // pA holds h1 (chunk x 128) and h3 (chunk x 256): chunk*512 u16
    // pB holds h2 (chunk x 384): chunk*768 u16
    size_t need_full = (fixed + (size_t)N_LEAVES * 512 + (size_t)N_LEAVES * 768) * sizeof(u16);
    int chunk = (ws_size >= need_full) ? N_LEAVES : 8192;
    u16* pA = ws + fixed;
    u16* pB = pA + (size_t)chunk * 512;

    // ---- split prep ----
    split_kernel<<<1024, 256, 0, stream>>>(inputs, inh, inl, N_LEAVES * 64);
    split_kernel<<<32,  256, 0, stream>>>(W1,  w1h, w1l, 8192);
    split_kernel<<<192, 256, 0, stream>>>(W2,  w2h, w2l, 49152);
    split_kernel<<<384, 256, 0, stream>>>(W3,  w3h, w3l, 98304);
    split_kernel<<<128, 256, 0, stream>>>(Wp,  wph, wpl, 32768);
    split_kernel<<<64,  256, 0, stream>>>(Wand, wah, wal, 16384);
    split_kernel<<<64,  256, 0, stream>>>(Wor,  woh, wol, 16384);

    // ---- leaf MLP ----
    for (int c0 = 0; c0 < N_LEAVES; c0 += chunk) {
        const u16* aH = inh + (size_t)c0 * 64;
        const u16* aL = inl + (size_t)c0 * 64;
        gemm_bf<0><<<dim3(chunk / 128, 1), 256, 0, stream>>>(
            aH, aL, w1h, w1l, nullptr, nullptr, nullptr,
            pA, pA + (size_t)chunk * 128, chunk, 128, 64);
        gemm_bf<0><<<dim3(chunk / 128, 3), 256, 0, stream>>>(
            pA, pA + (size_t)chunk * 128, w2h, w2l, nullptr, nullptr, nullptr,
            pB, pB + (size_t)chunk * 384, chunk, 384, 128);
        gemm_bf<0><<<dim3(chunk / 128, 2), 256, 0, stream>>>(
            pB, pB + (size_t)chunk * 384, w3h, w3l, nullptr, nullptr, nullptr,
            pA, pA + (size_t)chunk * 256, chunk, 256, 384);
        gemm_bf<0><<<dim3(chunk / 128, 1), 256, 0, stream>>>(
            pA, pA + (size_t)chunk * 256, wph, wpl, nullptr, nullptr, nullptr,
            h4h + (size_t)c0 * 128, h4l + (size_t)c0 * 128, chunk, 128, 256);
    }

    // ---- tree reduction, level 7 down to 0 ----
    const u16* hinH = h4h;
    const u16* hinL = h4l;
    for (int lv = 7; lv >= 0; --lv) {
        int n = 1 << (2 * lv);
        int start = (n - 1) / 3;
        int Mr = n * 4;
        u16* outH = (lv & 1) ? pB : pA;
        u16* outL = outH + (size_t)n * 128;
        gemm_bf<1><<<dim3((Mr + 127) / 128, 1), 256, 0, stream>>>(
            hinH, hinL, wah, wal, woh, wol, ops + start,
            outH, outL, Mr, 128, 128);
        hinH = outH;
        hinL = outL;
    }

    // ---- readout ----
    readout_kernel<<<1, 128, 0, stream>>>(hinH, hinL,
        Rw1, Rb1, Rw2, Rb2, Rw3, Rb3, Rwp, Rbp, out);
}